// Round 7
// baseline (20225.215 us; speedup 1.0000x reference)
//
#include <hip/hip_runtime.h>
#include <math.h>

#define N_TOK 1024
#define DV    400
#define G4    1600
#define DWD   300
#define DPD   100
#define HID   512
#define FD    128
#define GWG   25     // workgroups per LSTM direction (all on XCD0)
#define EPW   16     // hidden elements per WG (DV / GWG)

__device__ __forceinline__ float sigmoidf_(float x){ return 1.0f/(1.0f+__expf(-x)); }
// overflow-safe fast tanh: exp of a NEGATIVE argument only
__device__ __forceinline__ float tanh_safe(float x){
    float t = __expf(-2.0f*fabsf(x));
    float r = (1.0f - t)/(1.0f + t);
    return copysignf(r, x);
}

#define LDA(p) __hip_atomic_load((p), __ATOMIC_RELAXED, __HIP_MEMORY_SCOPE_AGENT)

// ---------------- embedding gather: x[t] = [word_emb[wid], pos_emb[pid]] ----------------
__global__ void k_gather(const int* __restrict__ wid, const int* __restrict__ pid,
                         const float* __restrict__ wemb, const float* __restrict__ pemb,
                         float* __restrict__ x)
{
    int t = blockIdx.x;
    int w = wid[t], p = pid[t];
    for (int k = threadIdx.x; k < DV; k += blockDim.x){
        float v = (k < DWD) ? wemb[(long)w*DWD + k] : pemb[p*DPD + (k - DWD)];
        x[t*DV + k] = v;
    }
}

// ---------------- tiny transpose (U_1 -> U_1^T) ----------------
__global__ void k_transpose(const float* __restrict__ U, float* __restrict__ Ut, int n)
{
    int j = blockIdx.y*16 + threadIdx.y;
    int k = blockIdx.x*16 + threadIdx.x;
    if (j < n && k < n) Ut[j*n + k] = U[k*n + j];
}

// ---------------- fp32 NT GEMM: C[M][Nn] = A[M][K] * B[Nn][K]^T (+biases, relu) -------
__global__ __launch_bounds__(256) void k_gemm_nt(
    const float* __restrict__ A, const float* __restrict__ B,
    const float* __restrict__ bias1, const float* __restrict__ bias2,
    const float* __restrict__ rowbias, float* __restrict__ C,
    int M, int Nn, int K, int revA, int relu)
{
    const int BM = 64, BN = 64, BK = 16;
    __shared__ float As[BK][BM];
    __shared__ float Bs[BK][BN];
    int tid = threadIdx.x;
    int tx = tid & 15, ty = tid >> 4;
    int m0 = blockIdx.y*BM, n0 = blockIdx.x*BN;
    int lrow = tid >> 2;          // 0..63
    int lk   = (tid & 3) * 4;     // 0,4,8,12
    float acc[4][4] = {{0.f}};

    for (int k0 = 0; k0 < K; k0 += BK){
        int am = m0 + lrow; if (revA) am = M - 1 - am;
        const float4 av = *(const float4*)&A[(long)am*K + k0 + lk];
        const float4 bv = *(const float4*)&B[(long)(n0 + lrow)*K + k0 + lk];
        As[lk+0][lrow] = av.x; As[lk+1][lrow] = av.y; As[lk+2][lrow] = av.z; As[lk+3][lrow] = av.w;
        Bs[lk+0][lrow] = bv.x; Bs[lk+1][lrow] = bv.y; Bs[lk+2][lrow] = bv.z; Bs[lk+3][lrow] = bv.w;
        __syncthreads();
        #pragma unroll
        for (int kk = 0; kk < BK; ++kk){
            const float4 a = *(const float4*)&As[kk][ty*4];
            const float4 b = *(const float4*)&Bs[kk][tx*4];
            const float ar[4] = {a.x, a.y, a.z, a.w};
            const float br[4] = {b.x, b.y, b.z, b.w};
            #pragma unroll
            for (int i = 0; i < 4; ++i)
                #pragma unroll
                for (int j = 0; j < 4; ++j)
                    acc[i][j] += ar[i]*br[j];
        }
        __syncthreads();
    }

    #pragma unroll
    for (int i = 0; i < 4; ++i){
        int m = m0 + ty*4 + i;
        float rb = rowbias ? rowbias[m] : 0.0f;
        #pragma unroll
        for (int j = 0; j < 4; ++j){
            int n = n0 + tx*4 + j;
            float v = acc[i][j] + rb;
            if (bias1) v += bias1[n];
            if (bias2) v += bias2[n];
            if (relu)  v = fmaxf(v, 0.0f);
            C[(long)m*Nn + n] = v;
        }
    }
}

// ---------------- persistent BiLSTM — same-XCD L2 exchange + agent fallback ------------
// All 50 participating WGs self-select onto XCD0 (HW_REG_XCC_ID + ticket; capacity
// 2 WGs/CU x 32 CUs = 64 >= 50 so selection cannot starve; ranks >= 50 exit).
// Exchange slot = packed (tag<<32 | h bits), 8B. Producer DUAL-publishes: plain
// volatile store (write-through L1 -> shared XCD0 L2) AND agent-scope atomic store
// (IF$, the r3-proven path). Consumer polls fast with sc0 loads (bypass L1, hit the
// shared L2, ~300cy RT); after 96 misses falls back to agent-scope polling. Both
// stores carry identical bytes so any interleaving is value-safe.
// Weights: 25 float4/thread loaded via inline-asm global_load_dwordx4 — an asm result
// cannot be rematerialized, so values stay in VGPRs (r3/r6 sink-into-loop fixed).
#define REP25(M) M(0) M(1) M(2) M(3) M(4) M(5) M(6) M(7) M(8) M(9) M(10) M(11) \
                 M(12) M(13) M(14) M(15) M(16) M(17) M(18) M(19) M(20) M(21) M(22) M(23) M(24)
#define DECLW(i) float4 w##i;
#define LOADW(i) { const float4* p_ = (const float4*)wrow + (i); \
    asm volatile("global_load_dwordx4 %0, %1, off" : "=&v"(w##i) : "v"(p_)); }
#define DOTW(i)  { float4 hv = h4[i]; \
                   sum = fmaf(w##i.x, hv.x, sum); sum = fmaf(w##i.y, hv.y, sum); \
                   sum = fmaf(w##i.z, hv.z, sum); sum = fmaf(w##i.w, hv.w, sum); }

__global__ __launch_bounds__(256, 2) void k_lstm(
    const float* __restrict__ Whh_f, const float* __restrict__ Whh_b,
    const float* __restrict__ Xf, const float* __restrict__ Xb,
    const float* __restrict__ h0, const float* __restrict__ c0,
    float* __restrict__ hf, float* __restrict__ hb,
    unsigned long long* __restrict__ mbox, int* __restrict__ ticket)
{
    __shared__ __align__(16) float hA[DV];
    __shared__ __align__(16) float hB[DV];
    __shared__ __align__(16) float gs[EPW*4];   // gs[e*4+q] gate partials
    __shared__ int rank_s;

    unsigned xcc;
    asm volatile("s_getreg_b32 %0, hwreg(HW_REG_XCC_ID)" : "=s"(xcc));
    if (xcc != 0) return;                 // only XCD0 WGs participate (shared L2)

    int tid = threadIdx.x;
    if (tid == 0) rank_s = atomicAdd(ticket, 1);
    __syncthreads();
    int rank = rank_s;
    if (rank >= 2*GWG) return;            // not selected; frees the CU slot

    int dir = rank / GWG;
    int g   = rank % GWG;
    int j0  = g * EPW;
    const float* XX  = dir ? Xb : Xf;
    float*       hout= dir ? hb : hf;
    unsigned long long* mb = mbox + (size_t)dir * N_TOK * DV;

    // dot-role: row r = q*16+e (64 rows), 4 threads/row each covering 100 k-floats
    int r    = tid >> 2;            // 0..63
    int sub  = tid & 3;
    int q    = r >> 4;              // gate 0..3 (i,f,g,o)
    int e    = r & 15;              // element within WG slice
    int grow = q*DV + j0 + e;       // global gate row

    // weights -> 25 float4 VGPRs via asm loads (cannot be sunk/rematerialized)
    const float* wrow = (dir ? Whh_b : Whh_f) + (size_t)grow*DV + sub*100;
    REP25(DECLW)
    REP25(LOADW)
    asm volatile("s_waitcnt vmcnt(0)" ::: "memory");
    __builtin_amdgcn_sched_barrier(0);    // rule #18: no use may hoist above the wait

    // producer-role: threads 0..15 own element e=tid (gate combine + c,h state)
    float c_reg = (tid < EPW) ? c0[dir*DV + j0 + tid] : 0.0f;

    for (int idx = tid; idx < DV; idx += 256) hA[idx] = h0[dir*DV + idx];

    // poll-role: thread polls slot tid (and 256+tid if tid<144)
    int s0 = tid;
    int s1 = 256 + tid;
    bool own0  = (s0 >= j0) && (s0 < j0 + EPW);
    bool skip1 = (tid >= DV - 256) || ((s1 >= j0) && (s1 < j0 + EPW));
    __syncthreads();

    float xv_n = (sub == 0) ? XX[grow] : 0.0f;   // X prefetch for t=0

    bool dead = false;
    for (int t = 0; t < N_TOK; ++t){
        const float* hc = (t & 1) ? hB : hA;
        float*       hn = (t & 1) ? hA : hB;
        float xv = xv_n;

        // matvec: 100 MACs/thread, W in regs, h broadcast from LDS
        const float4* h4 = (const float4*)hc + sub*25;
        float sum = 0.0f;
        REP25(DOTW)
        sum += __shfl_xor(sum, 1, 4);
        sum += __shfl_xor(sum, 2, 4);
        if (sub == 0) gs[e*4 + q] = sum + xv;
        __syncthreads();

        // producers: combine gates, update c, dual-publish h
        if (tid < EPW){
            float4 gv = *(const float4*)&gs[tid*4];   // (i,f,g,o) pre-activations
            float iv = sigmoidf_(gv.x);
            float fv = sigmoidf_(gv.y);
            float gg = tanh_safe(gv.z);
            float ov = sigmoidf_(gv.w);
            c_reg = fv*c_reg + iv*gg;
            float hvv = ov * tanh_safe(c_reg);
            unsigned long long pk = (1ull << 32) | (unsigned long long)__float_as_uint(hvv);
            unsigned long long* mslot = mb + (size_t)t*DV + j0 + tid;
            *(volatile unsigned long long*)mslot = pk;          // fast path: shared L2
            __hip_atomic_store(mslot, pk,                        // safety net: IF$
                               __ATOMIC_RELAXED, __HIP_MEMORY_SCOPE_AGENT);
            hout[(long)t*DV + j0 + tid] = hvv;   // plain store for post-LSTM kernels
            hn[j0 + tid] = hvv;                  // own elements bypass mailbox
        }

        // X prefetch for t+1 (drains during the poll)
        if (sub == 0){
            int tn = (t + 1 < N_TOK) ? (t + 1) : t;
            xv_n = XX[(size_t)tn*G4 + grow];
        }

        // poll: fast sc0 loop (L2-hit RT), then agent-scope fallback
        {
            const unsigned long long* p0 = mb + (size_t)t*DV + s0;
            const unsigned long long* p1 = mb + (size_t)t*DV + ((tid < DV-256) ? s1 : s0);
            bool g0 = own0, g1 = skip1;
            int it = 0;
            while (!(g0 && g1) && it < 96){
                unsigned long long u0, u1;
                asm volatile("global_load_dwordx2 %0, %2, off sc0\n\t"
                             "global_load_dwordx2 %1, %3, off sc0\n\t"
                             "s_waitcnt vmcnt(0)"
                             : "=&v"(u0), "=&v"(u1)          // early-clobber: r4 bugfix
                             : "v"(p0), "v"(p1) : "memory");
                if (!g0 && (u0 >> 32)){ hn[s0] = __uint_as_float((unsigned)u0); g0 = true; }
                if (!g1 && (u1 >> 32)){ hn[s1] = __uint_as_float((unsigned)u1); g1 = true; }
                ++it;
            }
            if (!(g0 && g1) && !dead){
                int guard = 0;
                while (!(g0 && g1)){
                    if (!g0){
                        unsigned long long u = LDA(p0);
                        if (u >> 32){ hn[s0] = __uint_as_float((unsigned)u); g0 = true; }
                    }
                    if (!g1){
                        unsigned long long u = LDA(p1);
                        if (u >> 32){ hn[s1] = __uint_as_float((unsigned)u); g1 = true; }
                    }
                    if (++guard > (1 << 16)) { dead = true; break; }  // no-hang safety
                }
            }
        }
        __syncthreads();   // hn complete; hc free for next step's writers
    }
}

// ---------------- sr = sigmoid(concat(hf[t], hb[N-1-t])) ----------------
__global__ void k_sr(const float* __restrict__ hf, const float* __restrict__ hb,
                     float* __restrict__ sr)
{
    int t = blockIdx.x;
    for (int c = threadIdx.x; c < 2*DV; c += blockDim.x){
        float v = (c < DV) ? hf[t*DV + c] : hb[(N_TOK-1-t)*DV + (c - DV)];
        sr[t*2*DV + c] = 1.0f/(1.0f+__expf(-v));
    }
}

// ---------------- bvec[i] = dot(Hh[i], u2) ----------------
__global__ void k_bvec(const float* __restrict__ Hh, const float* __restrict__ u2,
                       float* __restrict__ bvec)
{
    int i = blockIdx.x;
    int lane = threadIdx.x;
    float v = Hh[i*FD + lane]*u2[lane] + Hh[i*FD + 64 + lane]*u2[64 + lane];
    v += __shfl_xor(v, 1, 64);
    v += __shfl_xor(v, 2, 64);
    v += __shfl_xor(v, 4, 64);
    v += __shfl_xor(v, 8, 64);
    v += __shfl_xor(v, 16, 64);
    v += __shfl_xor(v, 32, 64);
    if (lane == 0) bvec[i] = v;
}

extern "C" void kernel_launch(void* const* d_in, const int* in_sizes, int n_in,
                              void* d_out, int out_size, void* d_ws, size_t ws_size,
                              hipStream_t stream)
{
    const int*   word_ids = (const int*)  d_in[0];
    const int*   pos_ids  = (const int*)  d_in[1];
    const float* h0    = (const float*)d_in[2];
    const float* c0    = (const float*)d_in[3];
    const float* wemb  = (const float*)d_in[4];
    const float* pemb  = (const float*)d_in[5];
    const float* Wih_f = (const float*)d_in[6];
    const float* Whh_f = (const float*)d_in[7];
    const float* bih_f = (const float*)d_in[8];
    const float* bhh_f = (const float*)d_in[9];
    const float* Wih_b = (const float*)d_in[10];
    const float* Whh_b = (const float*)d_in[11];
    const float* bih_b = (const float*)d_in[12];
    const float* bhh_b = (const float*)d_in[13];
    const float* Wh1   = (const float*)d_in[14];
    const float* bh1   = (const float*)d_in[15];
    const float* Wh2   = (const float*)d_in[16];
    const float* bh2   = (const float*)d_in[17];
    const float* Wd1   = (const float*)d_in[18];
    const float* bd1   = (const float*)d_in[19];
    const float* Wd2   = (const float*)d_in[20];
    const float* bd2   = (const float*)d_in[21];
    const float* U1    = (const float*)d_in[22];
    const float* u2    = (const float*)d_in[23];
    float* out = (float*)d_out;

    // workspace layout (floats)
    float* ws  = (float*)d_ws;
    float* x    = ws;                 // 1024*400
    float* Xf   = ws + 409600;        // 1024*1600
    float* Xb   = ws + 2048000;       // 1024*1600
    float* hf   = ws + 3686400;       // 1024*400
    float* hb   = ws + 4096000;       // 1024*400
    float* sr   = ws + 4505600;       // 1024*800   (aliased by mbox during LSTM)
    float* T1h  = ws + 5324800;       // 1024*512   (aliased by mbox during LSTM)
    float* T1d  = ws + 5849088;       // 1024*512   (partially aliased by mbox+ticket)
    float* Hh   = ws + 6373376;       // 1024*128
    float* Hd   = ws + 6504448;       // 1024*128
    float* G1   = ws + 6635520;       // 1024*128
    float* Ut   = ws + 6766592;       // 128*128
    float* bvec = ws + 6782976;       // 1024
    // mailbox: 2*1024*400 slots x 8B = 6.55 MB in floats [4505600, 6144000);
    // ticket right after. sr/T1h/T1d are written strictly after k_lstm completes.
    unsigned long long* mbox = (unsigned long long*)(ws + 4505600);
    int* ticket = (int*)(mbox + (size_t)2*N_TOK*DV);

    hipMemsetAsync(mbox, 0, (size_t)2*N_TOK*DV*sizeof(unsigned long long) + 16, stream);

    k_gather<<<N_TOK, 128, 0, stream>>>(word_ids, pos_ids, wemb, pemb, x);
    k_transpose<<<dim3(8,8), dim3(16,16), 0, stream>>>(U1, Ut, FD);

    dim3 blk(256);
    // input projections (recurrence-free): Xf/Xb = x((rev)) @ Wih^T + bih + bhh
    k_gemm_nt<<<dim3(G4/64, N_TOK/64), blk, 0, stream>>>(x, Wih_f, bih_f, bhh_f, nullptr, Xf,
                                                         N_TOK, G4, DV, 0, 0);
    k_gemm_nt<<<dim3(G4/64, N_TOK/64), blk, 0, stream>>>(x, Wih_b, bih_b, bhh_b, nullptr, Xb,
                                                         N_TOK, G4, DV, 1, 0);
    // sequential recurrence: oversubscribed launch; XCD0 WGs self-select via ticket
    k_lstm<<<1024, 256, 0, stream>>>(Whh_f, Whh_b, Xf, Xb, h0, c0, hf, hb, mbox, ticket);

    k_sr<<<N_TOK, 256, 0, stream>>>(hf, hb, sr);

    // MLPs
    k_gemm_nt<<<dim3(HID/64, N_TOK/64), blk, 0, stream>>>(sr, Wh1, bh1, nullptr, nullptr, T1h,
                                                          N_TOK, HID, 2*DV, 0, 1);
    k_gemm_nt<<<dim3(HID/64, N_TOK/64), blk, 0, stream>>>(sr, Wd1, bd1, nullptr, nullptr, T1d,
                                                          N_TOK, HID, 2*DV, 0, 1);
    k_gemm_nt<<<dim3(FD/64,  N_TOK/64), blk, 0, stream>>>(T1h, Wh2, bh2, nullptr, nullptr, Hh,
                                                          N_TOK, FD, HID, 0, 0);
    k_gemm_nt<<<dim3(FD/64,  N_TOK/64), blk, 0, stream>>>(T1d, Wd2, bd2, nullptr, nullptr, Hd,
                                                          N_TOK, FD, HID, 0, 0);
    // biaffine
    k_bvec<<<N_TOK, 64, 0, stream>>>(Hh, u2, bvec);
    k_gemm_nt<<<dim3(FD/64,  N_TOK/64), blk, 0, stream>>>(Hh, Ut, nullptr, nullptr, nullptr, G1,
                                                          N_TOK, FD, FD, 0, 0);
    k_gemm_nt<<<dim3(N_TOK/64, N_TOK/64), blk, 0, stream>>>(G1, Hd, nullptr, nullptr, bvec, out,
                                                            N_TOK, N_TOK, FD, 0, 0);
}

// Round 8
// 3824.904 us; speedup vs baseline: 5.2878x; 5.2878x over previous
//
#include <hip/hip_runtime.h>
#include <math.h>

#define N_TOK 1024
#define DV    400
#define G4    1600
#define DWD   300
#define DPD   100
#define HID   512
#define FD    128
#define GWG   50     // workgroups; each owns EPW elements of BOTH directions
#define EPW   8      // hidden elements per WG per direction
#define WPAD  201    // padded row stride in uint (2 bf16 per uint), kills 4-way bank conflict

__device__ __forceinline__ float sigmoidf_(float x){ return 1.0f/(1.0f+__expf(-x)); }
// overflow-safe fast tanh
__device__ __forceinline__ float tanh_safe(float x){
    float t = __expf(-2.0f*fabsf(x));
    float r = (1.0f - t)/(1.0f + t);
    return copysignf(r, x);
}
__device__ __forceinline__ unsigned f2bf(float f){   // RNE f32->bf16 (as low 16 bits)
    unsigned u = __float_as_uint(f);
    return (u + 0x7FFFu + ((u>>16)&1u)) >> 16;
}

#define LDA(p) __hip_atomic_load((p), __ATOMIC_RELAXED, __HIP_MEMORY_SCOPE_AGENT)

// ---------------- embedding gather ----------------
__global__ void k_gather(const int* __restrict__ wid, const int* __restrict__ pid,
                         const float* __restrict__ wemb, const float* __restrict__ pemb,
                         float* __restrict__ x)
{
    int t = blockIdx.x;
    int w = wid[t], p = pid[t];
    for (int k = threadIdx.x; k < DV; k += blockDim.x){
        float v = (k < DWD) ? wemb[(long)w*DWD + k] : pemb[p*DPD + (k - DWD)];
        x[t*DV + k] = v;
    }
}

// ---------------- tiny transpose (U_1 -> U_1^T) ----------------
__global__ void k_transpose(const float* __restrict__ U, float* __restrict__ Ut, int n)
{
    int j = blockIdx.y*16 + threadIdx.y;
    int k = blockIdx.x*16 + threadIdx.x;
    if (j < n && k < n) Ut[j*n + k] = U[k*n + j];
}

// ---------------- fp32 NT GEMM (single) ----------------
__global__ __launch_bounds__(256) void k_gemm_nt(
    const float* __restrict__ A, const float* __restrict__ B,
    const float* __restrict__ bias1, const float* __restrict__ rowbias,
    float* __restrict__ C, int M, int Nn, int K)
{
    const int BM = 64, BN = 64, BK = 16;
    __shared__ float As[BK][BM];
    __shared__ float Bs[BK][BN];
    int tid = threadIdx.x;
    int tx = tid & 15, ty = tid >> 4;
    int m0 = blockIdx.y*BM, n0 = blockIdx.x*BN;
    int lrow = tid >> 2, lk = (tid & 3) * 4;
    float acc[4][4] = {{0.f}};
    for (int k0 = 0; k0 < K; k0 += BK){
        const float4 av = *(const float4*)&A[(long)(m0+lrow)*K + k0 + lk];
        const float4 bv = *(const float4*)&B[(long)(n0+lrow)*K + k0 + lk];
        As[lk+0][lrow]=av.x; As[lk+1][lrow]=av.y; As[lk+2][lrow]=av.z; As[lk+3][lrow]=av.w;
        Bs[lk+0][lrow]=bv.x; Bs[lk+1][lrow]=bv.y; Bs[lk+2][lrow]=bv.z; Bs[lk+3][lrow]=bv.w;
        __syncthreads();
        #pragma unroll
        for (int kk = 0; kk < BK; ++kk){
            const float4 a = *(const float4*)&As[kk][ty*4];
            const float4 b = *(const float4*)&Bs[kk][tx*4];
            const float ar[4]={a.x,a.y,a.z,a.w}, br[4]={b.x,b.y,b.z,b.w};
            #pragma unroll
            for (int i=0;i<4;++i)
                #pragma unroll
                for (int j=0;j<4;++j) acc[i][j] += ar[i]*br[j];
        }
        __syncthreads();
    }
    #pragma unroll
    for (int i=0;i<4;++i){
        int m = m0 + ty*4 + i;
        float rb = rowbias ? rowbias[m] : 0.0f;
        #pragma unroll
        for (int j=0;j<4;++j){
            int n = n0 + tx*4 + j;
            float v = acc[i][j] + rb;
            if (bias1) v += bias1[n];
            C[(long)m*Nn + n] = v;
        }
    }
}

// ---------------- fp32 NT GEMM, z-merged pair (blockIdx.z picks the set) -------------
__global__ __launch_bounds__(256) void k_gemm_ntz(
    const float* __restrict__ A0, const float* __restrict__ A1,
    const float* __restrict__ B0, const float* __restrict__ B1,
    const float* __restrict__ c10, const float* __restrict__ c11,
    const float* __restrict__ c20, const float* __restrict__ c21,
    float* __restrict__ C0, float* __restrict__ C1,
    int M, int Nn, int K, int rev1, int relu)
{
    const float* A = blockIdx.z ? A1 : A0;
    const float* B = blockIdx.z ? B1 : B0;
    const float* bias1 = blockIdx.z ? c11 : c10;
    const float* bias2 = blockIdx.z ? c21 : c20;
    float* C = blockIdx.z ? C1 : C0;
    int revA = blockIdx.z ? rev1 : 0;

    const int BM = 64, BN = 64, BK = 16;
    __shared__ float As[BK][BM];
    __shared__ float Bs[BK][BN];
    int tid = threadIdx.x;
    int tx = tid & 15, ty = tid >> 4;
    int m0 = blockIdx.y*BM, n0 = blockIdx.x*BN;
    int lrow = tid >> 2, lk = (tid & 3) * 4;
    float acc[4][4] = {{0.f}};
    for (int k0 = 0; k0 < K; k0 += BK){
        int am = m0 + lrow; if (revA) am = M - 1 - am;
        const float4 av = *(const float4*)&A[(long)am*K + k0 + lk];
        const float4 bv = *(const float4*)&B[(long)(n0+lrow)*K + k0 + lk];
        As[lk+0][lrow]=av.x; As[lk+1][lrow]=av.y; As[lk+2][lrow]=av.z; As[lk+3][lrow]=av.w;
        Bs[lk+0][lrow]=bv.x; Bs[lk+1][lrow]=bv.y; Bs[lk+2][lrow]=bv.z; Bs[lk+3][lrow]=bv.w;
        __syncthreads();
        #pragma unroll
        for (int kk = 0; kk < BK; ++kk){
            const float4 a = *(const float4*)&As[kk][ty*4];
            const float4 b = *(const float4*)&Bs[kk][tx*4];
            const float ar[4]={a.x,a.y,a.z,a.w}, br[4]={b.x,b.y,b.z,b.w};
            #pragma unroll
            for (int i=0;i<4;++i)
                #pragma unroll
                for (int j=0;j<4;++j) acc[i][j] += ar[i]*br[j];
        }
        __syncthreads();
    }
    #pragma unroll
    for (int i=0;i<4;++i){
        int m = m0 + ty*4 + i;
        #pragma unroll
        for (int j=0;j<4;++j){
            int n = n0 + tx*4 + j;
            float v = acc[i][j];
            if (bias1) v += bias1[n];
            if (bias2) v += bias2[n];
            if (relu)  v = fmaxf(v, 0.0f);
            C[(long)m*Nn + n] = v;
        }
    }
}

// -------- persistent fused BiLSTM: both directions per WG, comm hidden under work -----
// Each WG owns elements [j0,j0+8) of BOTH directions. Per cycle (= one t for each dir):
//   dotF -> publish F[t] -> dotB -> publish B[t] -> poll F&B concurrently -> 1 barrier.
// The B-dot and both polls overlap F's store/load flight: ~2 steps per comm latency.
// Weights live in LDS as bf16 (rows padded to WPAD uints: bank-conflict-free), h fp32.
// Mailbox: r3-proven relaxed agent-scope 8B (tag<<32|h) slots; k_sr reads them directly.
__global__ __launch_bounds__(256) void k_lstm(
    const float* __restrict__ Whh_f, const float* __restrict__ Whh_b,
    const float* __restrict__ Xf, const float* __restrict__ Xb,
    const float* __restrict__ h0, const float* __restrict__ c0,
    unsigned long long* __restrict__ mbox)
{
    __shared__ unsigned Wf_u[32*WPAD];     // 25.7 KB (bf16 pairs)
    __shared__ unsigned Wb_u[32*WPAD];     // 25.7 KB
    __shared__ float hFA[DV], hFB[DV], hBA[DV], hBB[DV];   // 6.4 KB

    int tid = threadIdx.x;
    int g   = blockIdx.x;
    int j0  = g * EPW;
    unsigned long long* mbF = mbox;
    unsigned long long* mbB = mbox + (size_t)N_TOK * DV;

    // stage weights (bf16 pack): local row r = q*8+e -> global row q*DV + j0 + e
    for (int pid = tid; pid < 32*200; pid += 256){
        int rr = pid / 200, wk = pid % 200;
        int grow_ = (rr >> 3)*DV + j0 + (rr & 7);
        const float* wf = &Whh_f[(size_t)grow_*DV + 2*wk];
        const float* wb = &Whh_b[(size_t)grow_*DV + 2*wk];
        Wf_u[rr*WPAD + wk] = f2bf(wf[0]) | (f2bf(wf[1]) << 16);
        Wb_u[rr*WPAD + wk] = f2bf(wb[0]) | (f2bf(wb[1]) << 16);
    }
    for (int idx = tid; idx < DV; idx += 256){
        hFA[idx] = h0[idx];
        hBA[idx] = h0[DV + idx];
    }

    // dot roles (r3-proven layout): 8 lanes/row
    int w    = tid >> 6;        // wave 0..3
    int lane = tid & 63;
    int q    = lane >> 4;       // gate 0..3 (i,f,g,o)
    int eo   = (lane >> 3) & 1;
    int l    = lane & 7;        // lane within row octet
    int e    = 2*w + eo;        // element 0..7
    int r    = q*8 + e;         // local row
    int grow = q*DV + j0 + e;   // global gate row (in 1600)
    bool owner = (q == 0) && (l == 0);
    float c_f = owner ? c0[j0 + e]      : 0.0f;
    float c_b = owner ? c0[DV + j0 + e] : 0.0f;

    // poll roles: slots s0=tid, s1=256+tid (tid<144), for each direction
    int s0 = tid, s1 = 256 + tid;
    bool own0  = (s0 >= j0) && (s0 < j0 + EPW);
    bool skip1 = (tid >= DV - 256) || ((s1 >= j0) && (s1 < j0 + EPW));
    __syncthreads();

    float xvF_n = (l == 0) ? Xf[grow] : 0.0f;
    float xvB_n = (l == 0) ? Xb[grow] : 0.0f;

    bool dead = false;
    for (int t = 0; t < N_TOK; ++t){
        const float* hFc = (t & 1) ? hFB : hFA;
        float*       hFn = (t & 1) ? hFA : hFB;
        const float* hBc = (t & 1) ? hBB : hBA;
        float*       hBn = (t & 1) ? hBA : hBB;

        // ---------------- forward dot + publish ----------------
        {
            const float2* hc2 = (const float2*)hFc;
            const unsigned* wr = &Wf_u[r*WPAD + l];
            float sum = 0.0f;
            #pragma unroll
            for (int i = 0; i < 25; ++i){
                unsigned u = wr[8*i];
                float2 hv = hc2[l + 8*i];
                sum = fmaf(__uint_as_float(u << 16),        hv.x, sum);
                sum = fmaf(__uint_as_float(u & 0xFFFF0000u), hv.y, sum);
            }
            sum += __shfl_xor(sum, 1, 8);
            sum += __shfl_xor(sum, 2, 8);
            sum += __shfl_xor(sum, 4, 8);
            if (l == 0) sum += xvF_n;
            float gi = __shfl(sum, eo*8 + 0,  64);
            float gf = __shfl(sum, eo*8 + 16, 64);
            float gg = __shfl(sum, eo*8 + 32, 64);
            float go = __shfl(sum, eo*8 + 48, 64);
            if (owner){
                float iv = sigmoidf_(gi), fv = sigmoidf_(gf);
                float gv = tanh_safe(gg), ov = sigmoidf_(go);
                c_f = fv*c_f + iv*gv;
                float hvv = ov * tanh_safe(c_f);
                unsigned long long pk = (1ull<<32) | (unsigned long long)__float_as_uint(hvv);
                __hip_atomic_store(mbF + (size_t)t*DV + j0 + e, pk,
                                   __ATOMIC_RELAXED, __HIP_MEMORY_SCOPE_AGENT);
                hFn[j0 + e] = hvv;
            }
        }
        // prefetch F X for t+1 (flight hides under B-dot + polls)
        if (l == 0){
            int tn = (t + 1 < N_TOK) ? (t + 1) : t;
            xvF_n = Xf[(size_t)tn*G4 + grow];
        }

        // ---------------- backward dot + publish ----------------
        {
            const float2* hc2 = (const float2*)hBc;
            const unsigned* wr = &Wb_u[r*WPAD + l];
            float sum = 0.0f;
            #pragma unroll
            for (int i = 0; i < 25; ++i){
                unsigned u = wr[8*i];
                float2 hv = hc2[l + 8*i];
                sum = fmaf(__uint_as_float(u << 16),        hv.x, sum);
                sum = fmaf(__uint_as_float(u & 0xFFFF0000u), hv.y, sum);
            }
            sum += __shfl_xor(sum, 1, 8);
            sum += __shfl_xor(sum, 2, 8);
            sum += __shfl_xor(sum, 4, 8);
            if (l == 0) sum += xvB_n;
            float gi = __shfl(sum, eo*8 + 0,  64);
            float gf = __shfl(sum, eo*8 + 16, 64);
            float gg = __shfl(sum, eo*8 + 32, 64);
            float go = __shfl(sum, eo*8 + 48, 64);
            if (owner){
                float iv = sigmoidf_(gi), fv = sigmoidf_(gf);
                float gv = tanh_safe(gg), ov = sigmoidf_(go);
                c_b = fv*c_b + iv*gv;
                float hvv = ov * tanh_safe(c_b);
                unsigned long long pk = (1ull<<32) | (unsigned long long)__float_as_uint(hvv);
                __hip_atomic_store(mbB + (size_t)t*DV + j0 + e, pk,
                                   __ATOMIC_RELAXED, __HIP_MEMORY_SCOPE_AGENT);
                hBn[j0 + e] = hvv;
            }
        }
        if (l == 0){
            int tn = (t + 1 < N_TOK) ? (t + 1) : t;
            xvB_n = Xb[(size_t)tn*G4 + grow];
        }

        // ---------------- concurrent quad poll (F:s0,s1 + B:s0,s1) ----------------
        if (!dead){
            const unsigned long long* pF0 = mbF + (size_t)t*DV + s0;
            const unsigned long long* pF1 = mbF + (size_t)t*DV + ((tid < DV-256) ? s1 : s0);
            const unsigned long long* pB0 = mbB + (size_t)t*DV + s0;
            const unsigned long long* pB1 = mbB + (size_t)t*DV + ((tid < DV-256) ? s1 : s0);
            bool f0 = own0, f1 = skip1, b0 = own0, b1 = skip1;
            int guard = 0;
            while (!(f0 && f1 && b0 && b1)){
                if (!f0){ unsigned long long u = LDA(pF0);
                    if (u >> 32){ hFn[s0] = __uint_as_float((unsigned)u); f0 = true; } }
                if (!f1){ unsigned long long u = LDA(pF1);
                    if (u >> 32){ hFn[s1] = __uint_as_float((unsigned)u); f1 = true; } }
                if (!b0){ unsigned long long u = LDA(pB0);
                    if (u >> 32){ hBn[s0] = __uint_as_float((unsigned)u); b0 = true; } }
                if (!b1){ unsigned long long u = LDA(pB1);
                    if (u >> 32){ hBn[s1] = __uint_as_float((unsigned)u); b1 = true; } }
                if (++guard > (1 << 18)) { dead = true; break; }   // no-hang safety
            }
        }
        __syncthreads();   // hFn/hBn complete; cur buffers free for next cycle
    }
}

// ---------------- sr = sigmoid(concat(hF[t], hB[N-1-t])) from the mailbox ------------
__global__ void k_sr(const unsigned long long* __restrict__ mbox, float* __restrict__ sr)
{
    int t = blockIdx.x;
    const unsigned long long* mbF = mbox;
    const unsigned long long* mbB = mbox + (size_t)N_TOK * DV;
    for (int c = threadIdx.x; c < 2*DV; c += blockDim.x){
        unsigned long long u = (c < DV)
            ? LDA(mbF + (size_t)t*DV + c)
            : LDA(mbB + (size_t)(N_TOK-1-t)*DV + (c - DV));
        float v = __uint_as_float((unsigned)u);
        sr[t*2*DV + c] = 1.0f/(1.0f+__expf(-v));
    }
}

// ---------------- bvec[i] = dot(Hh[i], u2) ----------------
__global__ void k_bvec(const float* __restrict__ Hh, const float* __restrict__ u2,
                       float* __restrict__ bvec)
{
    int i = blockIdx.x;
    int lane = threadIdx.x;
    float v = Hh[i*FD + lane]*u2[lane] + Hh[i*FD + 64 + lane]*u2[64 + lane];
    v += __shfl_xor(v, 1, 64);
    v += __shfl_xor(v, 2, 64);
    v += __shfl_xor(v, 4, 64);
    v += __shfl_xor(v, 8, 64);
    v += __shfl_xor(v, 16, 64);
    v += __shfl_xor(v, 32, 64);
    if (lane == 0) bvec[i] = v;
}

extern "C" void kernel_launch(void* const* d_in, const int* in_sizes, int n_in,
                              void* d_out, int out_size, void* d_ws, size_t ws_size,
                              hipStream_t stream)
{
    const int*   word_ids = (const int*)  d_in[0];
    const int*   pos_ids  = (const int*)  d_in[1];
    const float* h0    = (const float*)d_in[2];
    const float* c0    = (const float*)d_in[3];
    const float* wemb  = (const float*)d_in[4];
    const float* pemb  = (const float*)d_in[5];
    const float* Wih_f = (const float*)d_in[6];
    const float* Whh_f = (const float*)d_in[7];
    const float* bih_f = (const float*)d_in[8];
    const float* bhh_f = (const float*)d_in[9];
    const float* Wih_b = (const float*)d_in[10];
    const float* Whh_b = (const float*)d_in[11];
    const float* bih_b = (const float*)d_in[12];
    const float* bhh_b = (const float*)d_in[13];
    const float* Wh1   = (const float*)d_in[14];
    const float* bh1   = (const float*)d_in[15];
    const float* Wh2   = (const float*)d_in[16];
    const float* bh2   = (const float*)d_in[17];
    const float* Wd1   = (const float*)d_in[18];
    const float* bd1   = (const float*)d_in[19];
    const float* Wd2   = (const float*)d_in[20];
    const float* bd2   = (const float*)d_in[21];
    const float* U1    = (const float*)d_in[22];
    const float* u2    = (const float*)d_in[23];
    float* out = (float*)d_out;

    // workspace layout (floats)
    float* ws  = (float*)d_ws;
    float* x    = ws;                 // 1024*400
    float* Xf   = ws + 409600;        // 1024*1600
    float* Xb   = ws + 2048000;       // 1024*1600
    float* sr   = ws + 4505600;       // 1024*800   (after mbox region is retired? no —
                                      //  mbox aliases [4505600,6144000); sr is written
                                      //  only AFTER k_lstm+k_sr read the mailbox)
    float* T1h  = ws + 6144000;       // 1024*512
    float* T1d  = ws + 6668288;       // 1024*512
    float* Hh   = ws + 7192576;       // 1024*128
    float* Hd   = ws + 7323648;       // 1024*128
    float* G1   = ws + 7454720;       // 1024*128
    float* Ut   = ws + 7585792;       // 128*128
    float* bvec = ws + 7602176;       // 1024
    // mailbox: 2*1024*400 slots x 8B = 6.55 MB in floats [3686400? no] -> place it
    // in its own region BELOW sr to avoid any overlap while k_sr reads it:
    unsigned long long* mbox = (unsigned long long*)(ws + 3686400); // [3686400,5324800)
    // NOTE: sr at 4505600 overlaps mbox! Move sr write AFTER all mailbox reads:
    // k_sr reads mbox and writes sr -> sr must NOT alias mbox. Fix: sr above mbox:
    sr = ws + 5324800;                // 1024*800, [5324800,6144000) — no overlap

    hipMemsetAsync(mbox, 0, (size_t)2*N_TOK*DV*sizeof(unsigned long long), stream);

    k_gather<<<N_TOK, 128, 0, stream>>>(word_ids, pos_ids, wemb, pemb, x);
    k_transpose<<<dim3(8,8), dim3(16,16), 0, stream>>>(U1, Ut, FD);

    dim3 blk(256);
    // input projections, z-merged: Xf = x@Wih_f^T + bih_f + bhh_f ; Xb = rev(x)@Wih_b^T + ...
    k_gemm_ntz<<<dim3(G4/64, N_TOK/64, 2), blk, 0, stream>>>(
        x, x, Wih_f, Wih_b, bih_f, bih_b, bhh_f, bhh_b, Xf, Xb,
        N_TOK, G4, DV, 1, 0);

    // fused two-direction recurrence
    k_lstm<<<GWG, 256, 0, stream>>>(Whh_f, Whh_b, Xf, Xb, h0, c0, mbox);

    k_sr<<<N_TOK, 256, 0, stream>>>(mbox, sr);

    // MLP layer 1 (z-merged, relu)
    k_gemm_ntz<<<dim3(HID/64, N_TOK/64, 2), blk, 0, stream>>>(
        sr, sr, Wh1, Wd1, bh1, bd1, nullptr, nullptr, T1h, T1d,
        N_TOK, HID, 2*DV, 0, 1);
    // MLP layer 2 (z-merged)
    k_gemm_ntz<<<dim3(FD/64, N_TOK/64, 2), blk, 0, stream>>>(
        T1h, T1d, Wh2, Wd2, bh2, bd2, nullptr, nullptr, Hh, Hd,
        N_TOK, FD, HID, 0, 0);
    // biaffine
    k_bvec<<<N_TOK, 64, 0, stream>>>(Hh, u2, bvec);
    k_gemm_nt<<<dim3(FD/64,  N_TOK/64), blk, 0, stream>>>(Hh, Ut, nullptr, nullptr, G1,
                                                          N_TOK, FD, FD);
    k_gemm_nt<<<dim3(N_TOK/64, N_TOK/64), blk, 0, stream>>>(G1, Hd, nullptr, bvec, out,
                                                            N_TOK, N_TOK, FD);
}

// Round 9
// 2925.986 us; speedup vs baseline: 6.9123x; 1.3072x over previous
//
#include <hip/hip_runtime.h>
#include <math.h>

#define N_TOK 1024
#define DV    400
#define G4    1600
#define DWD   300
#define DPD   100
#define HID   512
#define FD    128
#define GWG   50     // workgroups per LSTM direction (100 total)
#define EPW   8      // hidden elements per WG per direction
#define NCHK  (DV/4) // 100 poll chunks of 4 slots

typedef unsigned uint32x4 __attribute__((ext_vector_type(4)));

__device__ __forceinline__ float sigmoidf_(float x){ return 1.0f/(1.0f+__expf(-x)); }
// overflow-safe fast tanh
__device__ __forceinline__ float tanh_safe(float x){
    float t = __expf(-2.0f*fabsf(x));
    float r = (1.0f - t)/(1.0f + t);
    return copysignf(r, x);
}

#define LDA4(p) __hip_atomic_load((p), __ATOMIC_RELAXED, __HIP_MEMORY_SCOPE_AGENT)

// ring poll primitives: load keeps prior contents live ("+&v") so an early waitcnt
// can only ever observe zero-init or a genuine sample (both safe); the waitcnt asm
// carries a register dependency so checks cannot hoist above it (rule #18).
#define PLD(X, P) asm volatile("global_load_dwordx4 %0, %1, off sc0 sc1" \
                               : "+&v"(X) : "v"(P) : "memory")
#define PWT(X)    asm volatile("s_waitcnt vmcnt(2)" : "+v"(X) :: "memory")

// ---------------- embedding gather ----------------
__global__ void k_gather(const int* __restrict__ wid, const int* __restrict__ pid,
                         const float* __restrict__ wemb, const float* __restrict__ pemb,
                         float* __restrict__ x)
{
    int t = blockIdx.x;
    int w = wid[t], p = pid[t];
    for (int k = threadIdx.x; k < DV; k += blockDim.x){
        float v = (k < DWD) ? wemb[(long)w*DWD + k] : pemb[p*DPD + (k - DWD)];
        x[t*DV + k] = v;
    }
}

// ---------------- tiny transpose (U_1 -> U_1^T) ----------------
__global__ void k_transpose(const float* __restrict__ U, float* __restrict__ Ut, int n)
{
    int j = blockIdx.y*16 + threadIdx.y;
    int k = blockIdx.x*16 + threadIdx.x;
    if (j < n && k < n) Ut[j*n + k] = U[k*n + j];
}

// ---------------- fp32 NT GEMM (single) ----------------
__global__ __launch_bounds__(256) void k_gemm_nt(
    const float* __restrict__ A, const float* __restrict__ B,
    const float* __restrict__ bias1, const float* __restrict__ rowbias,
    float* __restrict__ C, int M, int Nn, int K)
{
    const int BM = 64, BN = 64, BK = 16;
    __shared__ float As[BK][BM];
    __shared__ float Bs[BK][BN];
    int tid = threadIdx.x;
    int tx = tid & 15, ty = tid >> 4;
    int m0 = blockIdx.y*BM, n0 = blockIdx.x*BN;
    int lrow = tid >> 2, lk = (tid & 3) * 4;
    float acc[4][4] = {{0.f}};
    for (int k0 = 0; k0 < K; k0 += BK){
        const float4 av = *(const float4*)&A[(long)(m0+lrow)*K + k0 + lk];
        const float4 bv = *(const float4*)&B[(long)(n0+lrow)*K + k0 + lk];
        As[lk+0][lrow]=av.x; As[lk+1][lrow]=av.y; As[lk+2][lrow]=av.z; As[lk+3][lrow]=av.w;
        Bs[lk+0][lrow]=bv.x; Bs[lk+1][lrow]=bv.y; Bs[lk+2][lrow]=bv.z; Bs[lk+3][lrow]=bv.w;
        __syncthreads();
        #pragma unroll
        for (int kk = 0; kk < BK; ++kk){
            const float4 a = *(const float4*)&As[kk][ty*4];
            const float4 b = *(const float4*)&Bs[kk][tx*4];
            const float ar[4]={a.x,a.y,a.z,a.w}, br[4]={b.x,b.y,b.z,b.w};
            #pragma unroll
            for (int i=0;i<4;++i)
                #pragma unroll
                for (int j=0;j<4;++j) acc[i][j] += ar[i]*br[j];
        }
        __syncthreads();
    }
    #pragma unroll
    for (int i=0;i<4;++i){
        int m = m0 + ty*4 + i;
        float rb = rowbias ? rowbias[m] : 0.0f;
        #pragma unroll
        for (int j=0;j<4;++j){
            int n = n0 + tx*4 + j;
            float v = acc[i][j] + rb;
            if (bias1) v += bias1[n];
            C[(long)m*Nn + n] = v;
        }
    }
}

// ---------------- fp32 NT GEMM, z-merged pair ----------------
__global__ __launch_bounds__(256) void k_gemm_ntz(
    const float* __restrict__ A0, const float* __restrict__ A1,
    const float* __restrict__ B0, const float* __restrict__ B1,
    const float* __restrict__ c10, const float* __restrict__ c11,
    const float* __restrict__ c20, const float* __restrict__ c21,
    float* __restrict__ C0, float* __restrict__ C1,
    int M, int Nn, int K, int rev1, int relu)
{
    const float* A = blockIdx.z ? A1 : A0;
    const float* B = blockIdx.z ? B1 : B0;
    const float* bias1 = blockIdx.z ? c11 : c10;
    const float* bias2 = blockIdx.z ? c21 : c20;
    float* C = blockIdx.z ? C1 : C0;
    int revA = blockIdx.z ? rev1 : 0;

    const int BM = 64, BN = 64, BK = 16;
    __shared__ float As[BK][BM];
    __shared__ float Bs[BK][BN];
    int tid = threadIdx.x;
    int tx = tid & 15, ty = tid >> 4;
    int m0 = blockIdx.y*BM, n0 = blockIdx.x*BN;
    int lrow = tid >> 2, lk = (tid & 3) * 4;
    float acc[4][4] = {{0.f}};
    for (int k0 = 0; k0 < K; k0 += BK){
        int am = m0 + lrow; if (revA) am = M - 1 - am;
        const float4 av = *(const float4*)&A[(long)am*K + k0 + lk];
        const float4 bv = *(const float4*)&B[(long)(n0+lrow)*K + k0 + lk];
        As[lk+0][lrow]=av.x; As[lk+1][lrow]=av.y; As[lk+2][lrow]=av.z; As[lk+3][lrow]=av.w;
        Bs[lk+0][lrow]=bv.x; Bs[lk+1][lrow]=bv.y; Bs[lk+2][lrow]=bv.z; Bs[lk+3][lrow]=bv.w;
        __syncthreads();
        #pragma unroll
        for (int kk = 0; kk < BK; ++kk){
            const float4 a = *(const float4*)&As[kk][ty*4];
            const float4 b = *(const float4*)&Bs[kk][tx*4];
            const float ar[4]={a.x,a.y,a.z,a.w}, br[4]={b.x,b.y,b.z,b.w};
            #pragma unroll
            for (int i=0;i<4;++i)
                #pragma unroll
                for (int j=0;j<4;++j) acc[i][j] += ar[i]*br[j];
        }
        __syncthreads();
    }
    #pragma unroll
    for (int i=0;i<4;++i){
        int m = m0 + ty*4 + i;
        #pragma unroll
        for (int j=0;j<4;++j){
            int n = n0 + tx*4 + j;
            float v = acc[i][j];
            if (bias1) v += bias1[n];
            if (bias2) v += bias2[n];
            if (relu)  v = fmaxf(v, 0.0f);
            C[(long)m*Nn + n] = v;
        }
    }
}

// ---------------- persistent BiLSTM — r3 structure + 4B slots + dwordx4 ring poll -----
// 100 WGs (50/dir), each owns EPW=8 elements = 32 gate rows of Whh (fp32 LDS, r3-proven
// layout). Mailbox slot = bits(h)|1 (4B, memset-0 = empty; LSB forced, err<6e-8).
// Producers: one relaxed agent-scope 4B atomic store per element. Consumers: 100 poller
// threads each own one 16B chunk (4 slots), sampled with a depth-3 global_load_dwordx4
// ring primed BEFORE the dot; fast-path cap 64 iters then r3-proven per-slot fallback.
__global__ __launch_bounds__(256) void k_lstm(
    const float* __restrict__ Whh_f, const float* __restrict__ Whh_b,
    const float* __restrict__ Xf, const float* __restrict__ Xb,
    const float* __restrict__ h0, const float* __restrict__ c0,
    unsigned* __restrict__ mbox)
{
    __shared__ float W_s[32][DV];                 // 51.2 KB
    __shared__ __align__(16) float hA[DV];
    __shared__ __align__(16) float hB[DV];

    int tid = threadIdx.x;
    int dir = blockIdx.x / GWG;
    int g   = blockIdx.x % GWG;
    int j0  = g * EPW;
    const float* Whh = dir ? Whh_b : Whh_f;
    const float* XX  = dir ? Xb    : Xf;
    unsigned* mb = mbox + (size_t)dir * N_TOK * DV;

    // stage weight slice: local row r = q*8+e -> global gate row q*DV + j0 + e
    for (int idx = tid; idx < 32*DV; idx += 256){
        int rr = idx / DV, k = idx % DV;
        int grow_ = (rr >> 3) * DV + j0 + (rr & 7);
        W_s[rr][k] = Whh[(long)grow_*DV + k];
    }
    for (int idx = tid; idx < DV; idx += 256) hA[idx] = h0[dir*DV + idx];

    // dot roles (r3-proven): 8 lanes/row
    int w    = tid >> 6;        // wave 0..3
    int lane = tid & 63;
    int q    = lane >> 4;       // gate 0..3 (i,f,g,o)
    int eo   = (lane >> 3) & 1;
    int l    = lane & 7;        // lane within row octet
    int e    = 2*w + eo;        // element 0..7
    int r    = q*8 + e;         // local weight row
    int grow = q*DV + j0 + e;   // global gate row
    bool owner = (q == 0) && (l == 0);
    float c_reg = owner ? c0[dir*DV + j0 + e] : 0.0f;

    // poll role: threads 0..99 own chunk cid (4 slots); own-WG chunks are skipped
    int  cid   = tid;
    bool isPoll = (tid < NCHK) && (cid != 2*g) && (cid != 2*g + 1);
    __syncthreads();

    float xv_n = (l == 0) ? XX[grow] : 0.0f;   // X prefetch for t=0

    bool dead = false;
    for (int t = 0; t < N_TOK; ++t){
        const float* hc = (t & 1) ? hB : hA;
        float*       hn = (t & 1) ? hA : hB;

        const unsigned* pc = mb + (size_t)t*DV + 4*cid;
        uint32x4 A = {0,0,0,0}, B = {0,0,0,0}, C = {0,0,0,0};
        if (isPoll){ PLD(A, pc); PLD(B, pc); PLD(C, pc); }   // primed before the dot

        float xv = xv_n;

        // matvec: row r dot h (8 lanes/row, float2 each, W fp32 in LDS)
        const float2* wrow = (const float2*)&W_s[r][0];
        const float2* hp   = (const float2*)hc;
        float sum = 0.0f;
        #pragma unroll
        for (int i = 0; i < 25; ++i){
            float2 wv = wrow[l + 8*i];
            float2 hv = hp[l + 8*i];
            sum = fmaf(wv.x, hv.x, sum);
            sum = fmaf(wv.y, hv.y, sum);
        }
        sum += __shfl_xor(sum, 1, 8);
        sum += __shfl_xor(sum, 2, 8);
        sum += __shfl_xor(sum, 4, 8);
        if (l == 0) sum += xv;

        // gather the 4 gate totals for my wave's element e
        float gi = __shfl(sum, eo*8 + 0,  64);
        float gf = __shfl(sum, eo*8 + 16, 64);
        float gg = __shfl(sum, eo*8 + 32, 64);
        float go = __shfl(sum, eo*8 + 48, 64);

        if (owner){
            float iv = sigmoidf_(gi), fv = sigmoidf_(gf);
            float gv = tanh_safe(gg), ov = sigmoidf_(go);
            c_reg = fv*c_reg + iv*gv;
            float hvv = ov * tanh_safe(c_reg);
            unsigned pk = __float_as_uint(hvv) | 1u;   // LSB=1 marks "arrived"
            __hip_atomic_store(mb + (size_t)t*DV + j0 + e, pk,
                               __ATOMIC_RELAXED, __HIP_MEMORY_SCOPE_AGENT);
            hn[j0 + e] = hvv;                          // own elements bypass mailbox
        }

        // X prefetch for t+1 (flight hides under the poll)
        if (l == 0){
            int tn = (t + 1 < N_TOK) ? (t + 1) : t;
            xv_n = XX[(size_t)tn*G4 + grow];
        }

        // fast ring poll: 4 slots per sample, depth-3 outstanding
        if (isPoll && !dead){
            bool got = false;
            uint32x4 R;
            int fast = 0;
            while (fast < 64){
                PWT(A); if (A.x && A.y && A.z && A.w){ R = A; got = true; break; }
                PLD(A, pc);
                PWT(B); if (B.x && B.y && B.z && B.w){ R = B; got = true; break; }
                PLD(B, pc);
                PWT(C); if (C.x && C.y && C.z && C.w){ R = C; got = true; break; }
                PLD(C, pc);
                fast += 3;
            }
            if (got){
                float4 f;
                f.x = __uint_as_float(R.x); f.y = __uint_as_float(R.y);
                f.z = __uint_as_float(R.z); f.w = __uint_as_float(R.w);
                *(float4*)&hn[4*cid] = f;
            } else {
                // fallback: r3-proven per-slot agent-scope polling
                bool d0=false,d1=false,d2=false,d3=false;
                int guard = 0;
                while (!(d0 && d1 && d2 && d3)){
                    if (!d0){ unsigned u = LDA4(pc+0); if (u){ hn[4*cid+0]=__uint_as_float(u); d0=true; } }
                    if (!d1){ unsigned u = LDA4(pc+1); if (u){ hn[4*cid+1]=__uint_as_float(u); d1=true; } }
                    if (!d2){ unsigned u = LDA4(pc+2); if (u){ hn[4*cid+2]=__uint_as_float(u); d2=true; } }
                    if (!d3){ unsigned u = LDA4(pc+3); if (u){ hn[4*cid+3]=__uint_as_float(u); d3=true; } }
                    if (++guard > (1 << 18)) { dead = true; break; }   // no-hang safety
                }
            }
        }
        __syncthreads();   // hn complete; hc free for next step's writers
    }
}

// ---------------- sr = sigmoid(concat(hF[t], hB[N-1-t])) straight from the mailbox ----
__global__ void k_sr(const float* __restrict__ mbox, float* __restrict__ sr)
{
    int t = blockIdx.x;
    const float* mF = mbox;
    const float* mB = mbox + (size_t)N_TOK * DV;
    for (int c = threadIdx.x; c < 2*DV; c += blockDim.x){
        float v = (c < DV) ? mF[(size_t)t*DV + c]
                           : mB[(size_t)(N_TOK-1-t)*DV + (c - DV)];
        sr[t*2*DV + c] = 1.0f/(1.0f+__expf(-v));
    }
}

// ---------------- bvec[i] = dot(Hh[i], u2) ----------------
__global__ void k_bvec(const float* __restrict__ Hh, const float* __restrict__ u2,
                       float* __restrict__ bvec)
{
    int i = blockIdx.x;
    int lane = threadIdx.x;
    float v = Hh[i*FD + lane]*u2[lane] + Hh[i*FD + 64 + lane]*u2[64 + lane];
    v += __shfl_xor(v, 1, 64);
    v += __shfl_xor(v, 2, 64);
    v += __shfl_xor(v, 4, 64);
    v += __shfl_xor(v, 8, 64);
    v += __shfl_xor(v, 16, 64);
    v += __shfl_xor(v, 32, 64);
    if (lane == 0) bvec[i] = v;
}

extern "C" void kernel_launch(void* const* d_in, const int* in_sizes, int n_in,
                              void* d_out, int out_size, void* d_ws, size_t ws_size,
                              hipStream_t stream)
{
    const int*   word_ids = (const int*)  d_in[0];
    const int*   pos_ids  = (const int*)  d_in[1];
    const float* h0    = (const float*)d_in[2];
    const float* c0    = (const float*)d_in[3];
    const float* wemb  = (const float*)d_in[4];
    const float* pemb  = (const float*)d_in[5];
    const float* Wih_f = (const float*)d_in[6];
    const float* Whh_f = (const float*)d_in[7];
    const float* bih_f = (const float*)d_in[8];
    const float* bhh_f = (const float*)d_in[9];
    const float* Wih_b = (const float*)d_in[10];
    const float* Whh_b = (const float*)d_in[11];
    const float* bih_b = (const float*)d_in[12];
    const float* bhh_b = (const float*)d_in[13];
    const float* Wh1   = (const float*)d_in[14];
    const float* bh1   = (const float*)d_in[15];
    const float* Wh2   = (const float*)d_in[16];
    const float* bh2   = (const float*)d_in[17];
    const float* Wd1   = (const float*)d_in[18];
    const float* bd1   = (const float*)d_in[19];
    const float* Wd2   = (const float*)d_in[20];
    const float* bd2   = (const float*)d_in[21];
    const float* U1    = (const float*)d_in[22];
    const float* u2    = (const float*)d_in[23];
    float* out = (float*)d_out;

    // workspace layout (floats)
    float* ws  = (float*)d_ws;
    float* x    = ws;                 // [0, 409600)
    float* Xf   = ws + 409600;        // [409600, 2048000)
    float* Xb   = ws + 2048000;       // [2048000, 3686400)
    unsigned* mbox = (unsigned*)(ws + 3686400);   // 2*1024*400 x 4B = [3686400, 4505600)
    float* sr   = ws + 4505600;       // [4505600, 5324800)
    float* T1h  = ws + 5324800;       // [5324800, 5849088)
    float* T1d  = ws + 5849088;       // [5849088, 6373376)
    float* Hh   = ws + 6373376;       // [6373376, 6504448)
    float* Hd   = ws + 6504448;       // [6504448, 6635520)
    float* G1   = ws + 6635520;       // [6635520, 6766592)
    float* Ut   = ws + 6766592;       // [6766592, 6782976)
    float* bvec = ws + 6782976;       // [6782976, 6784000)

    hipMemsetAsync(mbox, 0, (size_t)2*N_TOK*DV*sizeof(unsigned), stream);

    k_gather<<<N_TOK, 128, 0, stream>>>(word_ids, pos_ids, wemb, pemb, x);
    k_transpose<<<dim3(8,8), dim3(16,16), 0, stream>>>(U1, Ut, FD);

    dim3 blk(256);
    // input projections, z-merged: Xf = x@Wih_f^T + b..; Xb = rev(x)@Wih_b^T + b..
    k_gemm_ntz<<<dim3(G4/64, N_TOK/64, 2), blk, 0, stream>>>(
        x, x, Wih_f, Wih_b, bih_f, bih_b, bhh_f, bhh_b, Xf, Xb,
        N_TOK, G4, DV, 1, 0);

    // sequential recurrence: 100 WGs (50/dir)
    k_lstm<<<2*GWG, 256, 0, stream>>>(Whh_f, Whh_b, Xf, Xb, h0, c0, mbox);

    k_sr<<<N_TOK, 256, 0, stream>>>((const float*)mbox, sr);

    // MLP layer 1 (z-merged, relu) and layer 2 (z-merged)
    k_gemm_ntz<<<dim3(HID/64, N_TOK/64, 2), blk, 0, stream>>>(
        sr, sr, Wh1, Wd1, bh1, bd1, nullptr, nullptr, T1h, T1d,
        N_TOK, HID, 2*DV, 0, 1);
    k_gemm_ntz<<<dim3(FD/64, N_TOK/64, 2), blk, 0, stream>>>(
        T1h, T1d, Wh2, Wd2, bh2, bd2, nullptr, nullptr, Hh, Hd,
        N_TOK, FD, HID, 0, 0);
    // biaffine
    k_bvec<<<N_TOK, 64, 0, stream>>>(Hh, u2, bvec);
    k_gemm_nt<<<dim3(FD/64,  N_TOK/64), blk, 0, stream>>>(Hh, Ut, nullptr, nullptr, G1,
                                                          N_TOK, FD, FD);
    k_gemm_nt<<<dim3(N_TOK/64, N_TOK/64), blk, 0, stream>>>(G1, Hd, nullptr, bvec, out,
                                                            N_TOK, N_TOK, FD);
}